// Round 1
// baseline (247.375 us; speedup 1.0000x reference)
//
#include <hip/hip_runtime.h>

// Problem constants (from setup_inputs): bt=4, nv=20000, nf=40000, H=W=256, S=2048
#define BT   4
#define NV   20000
#define NF   40000
#define SMP  2048
#define NPIX (BT * 256 * 256)
#define NVG  (BT * NV)          // 80000 packed vertices
#define NCH  8                  // vertex chunks per batch for the main kernel
#define CHUNK ((NV + NCH - 1) / NCH)   // 2500

// Order-preserving float<->uint encoding (handles slightly-negative d2 from
// the expansion formula's cancellation).
__device__ __forceinline__ unsigned int enc_f32(float f) {
    unsigned int u = __float_as_uint(f);
    return (u & 0x80000000u) ? ~u : (u | 0x80000000u);
}
__device__ __forceinline__ float dec_f32(unsigned int k) {
    unsigned int u = (k & 0x80000000u) ? (k & 0x7FFFFFFFu) : ~k;
    return __uint_as_float(u);
}

// 1) init workspace: min-keys to +inf-encoding, per-batch invisible flags and
//    visibility array to 0. (harness poisons ws with 0xAA before every launch)
__global__ void init_k(unsigned int* __restrict__ minKeys,
                       int* __restrict__ flags,
                       float* __restrict__ visible) {
    int i = blockIdx.x * blockDim.x + threadIdx.x;
    if (i < BT * SMP) minKeys[i] = 0xFFFFFFFFu;
    if (i < BT)       flags[i]   = 0;
    if (i < NVG)      visible[i] = 0.0f;
}

// 2) visibility scatter: pixel -> face -> 3 vertices (global ids)
__global__ void vis_k(const int* __restrict__ p2f,
                      const int* __restrict__ faces,
                      float* __restrict__ visible) {
    int p = blockIdx.x * blockDim.x + threadIdx.x;
    if (p >= NPIX) return;
    int fi = p2f[p];
    if (fi < 0) return;
    int b    = fi / NF;           // faces_packed batch
    int base = fi * 3;
    int off  = b * NV;
    visible[faces[base + 0] + off] = 1.0f;   // idempotent racy stores: fine
    visible[faces[base + 1] + off] = 1.0f;
    visible[faces[base + 2] + off] = 1.0f;
}

// 3) pack verts as float4 {x,y,z, |v|^2 or 1e30 if invisible}; mark batches
//    that contain at least one invisible vertex.
__global__ void pack_k(const float* __restrict__ verts,
                       const float* __restrict__ visible,
                       float4* __restrict__ packed,
                       int* __restrict__ flags) {
    int i = blockIdx.x * blockDim.x + threadIdx.x;
    if (i >= NVG) return;
    float x = verts[3 * i + 0];
    float y = verts[3 * i + 1];
    float z = verts[3 * i + 2];
    float w;
    if (visible[i] > 0.0f) {
        w = x * x + y * y + z * z;
    } else {
        w = 1e30f;                 // never wins the min
        flags[i / NV] = 1;         // racy idempotent store
    }
    packed[i] = make_float4(x, y, z, w);
}

// 4) main: per (batch, sample) min over a vertex chunk, LDS-staged tiles.
__global__ __launch_bounds__(256) void
main_k(const float4* __restrict__ bds,
       const float4* __restrict__ packed,
       const int* __restrict__ flags,
       unsigned int* __restrict__ minKeys) {
    __shared__ float4 sh[256];
    const int b  = blockIdx.z;
    const int s  = blockIdx.y * 256 + threadIdx.x;
    const int v0 = blockIdx.x * CHUNK;
    const int v1 = min(v0 + CHUNK, NV);

    float4 p = bds[b * SMP + s];                 // {x,y,z,mask}
    float bs = p.x * p.x + p.y * p.y + p.z * p.z;
    float mn = 3.0e38f;

    const float4* vp = packed + b * NV;
    for (int t = v0; t < v1; t += 256) {
        int idx = t + threadIdx.x;
        if (idx < v1) sh[threadIdx.x] = vp[idx];
        __syncthreads();
        int cnt = min(256, v1 - t);
        #pragma unroll 8
        for (int j = 0; j < cnt; ++j) {
            float4 v  = sh[j];                              // LDS broadcast
            float dot = fmaf(p.x, v.x, fmaf(p.y, v.y, p.z * v.z));
            float d2  = fmaf(-2.0f, dot, bs + v.w);         // |p|^2+|v|^2-2dot
            mn = fminf(mn, d2);
        }
        __syncthreads();
    }
    if (flags[b]) mn = fminf(mn, 1000.0f);       // exact MASK_PENALTY path
    atomicMin(&minKeys[b * SMP + s], enc_f32(mn));
}

// 5) final reduce: sum(min * mask) / BT, single block.
__global__ void red_k(const unsigned int* __restrict__ minKeys,
                      const float* __restrict__ bds,
                      float* __restrict__ out) {
    const int tid = threadIdx.x;                 // blockDim = 1024
    float sum = 0.0f;
    for (int i = tid; i < BT * SMP; i += 1024) {
        float f = dec_f32(minKeys[i]);
        float m = bds[4 * i + 3];                // mask channel
        sum = fmaf(f, m, sum);
    }
    #pragma unroll
    for (int o = 32; o > 0; o >>= 1) sum += __shfl_down(sum, o, 64);
    __shared__ float part[16];
    if ((tid & 63) == 0) part[tid >> 6] = sum;
    __syncthreads();
    if (tid == 0) {
        float t = 0.0f;
        #pragma unroll
        for (int i = 0; i < 16; ++i) t += part[i];
        out[0] = t / (float)BT;
    }
}

extern "C" void kernel_launch(void* const* d_in, const int* in_sizes, int n_in,
                              void* d_out, int out_size, void* d_ws, size_t ws_size,
                              hipStream_t stream) {
    const float* verts = (const float*)d_in[0];   // (4,20000,3) f32
    const float* bds   = (const float*)d_in[1];   // (4,2048,4)  f32
    const int*   faces = (const int*)d_in[2];     // (4,40000,3) int
    const int*   p2f   = (const int*)d_in[3];     // (4,256,256,1) int
    float*       out   = (float*)d_out;

    // workspace layout
    char* ws = (char*)d_ws;
    unsigned int* minKeys = (unsigned int*)ws;                    // 32768 B
    int*    flags   = (int*)(ws + 32768);                         // 16 B
    float4* packed  = (float4*)(ws + 32800);                      // 1,280,000 B
    float*  visible = (float*)(ws + 32800 + 1280000);             // 320,000 B

    init_k<<<(NVG + 255) / 256, 256, 0, stream>>>(minKeys, flags, visible);
    vis_k<<<(NPIX + 255) / 256, 256, 0, stream>>>(p2f, faces, visible);
    pack_k<<<(NVG + 255) / 256, 256, 0, stream>>>(verts, visible, packed, flags);
    main_k<<<dim3(NCH, SMP / 256, BT), 256, 0, stream>>>(
        (const float4*)bds, packed, flags, minKeys);
    red_k<<<1, 1024, 0, stream>>>(minKeys, bds, out);
}

// Round 2
// 103.016 us; speedup vs baseline: 2.4013x; 2.4013x over previous
//
#include <hip/hip_runtime.h>

// Problem constants (from setup_inputs): bt=4, nv=20000, nf=40000, H=W=256, S=2048
#define BT   4
#define NV   20000
#define NF   40000
#define SMP  2048
#define NPIX (BT * 256 * 256)
#define NVG  (BT * NV)          // 80000 packed vertices
#define NCH  64                 // vertex chunks per batch for the main kernel
#define CHUNK ((NV + NCH - 1) / NCH)   // 313
#define P    8                  // samples per thread in main_k (256 thr * 8 = 2048)

// Order-preserving float<->uint encoding (handles negative q values).
__device__ __forceinline__ unsigned int enc_f32(float f) {
    unsigned int u = __float_as_uint(f);
    return (u & 0x80000000u) ? ~u : (u | 0x80000000u);
}
__device__ __forceinline__ float dec_f32(unsigned int k) {
    unsigned int u = (k & 0x80000000u) ? (k & 0x7FFFFFFFu) : ~k;
    return __uint_as_float(u);
}

// 1) init workspace: min-keys to +inf-encoding, per-batch invisible flags and
//    visibility array to 0. (harness poisons ws with 0xAA before every launch)
__global__ void init_k(unsigned int* __restrict__ minKeys,
                       int* __restrict__ flags,
                       float* __restrict__ visible) {
    int i = blockIdx.x * blockDim.x + threadIdx.x;
    if (i < BT * SMP) minKeys[i] = 0xFFFFFFFFu;
    if (i < BT)       flags[i]   = 0;
    if (i < NVG)      visible[i] = 0.0f;
}

// 2) visibility scatter: pixel -> face -> 3 vertices (global ids)
__global__ void vis_k(const int* __restrict__ p2f,
                      const int* __restrict__ faces,
                      float* __restrict__ visible) {
    int p = blockIdx.x * blockDim.x + threadIdx.x;
    if (p >= NPIX) return;
    int fi = p2f[p];
    if (fi < 0) return;
    int b    = fi / NF;           // faces_packed batch
    int base = fi * 3;
    int off  = b * NV;
    visible[faces[base + 0] + off] = 1.0f;   // idempotent racy stores: fine
    visible[faces[base + 1] + off] = 1.0f;
    visible[faces[base + 2] + off] = 1.0f;
}

// 3) pack verts as float4 {-2x,-2y,-2z, |v|^2 or 1e30 if invisible}.
//    q = dot(p, {-2x,-2y,-2z}) + w  ==  |v|^2 - 2<p,v>  (per-sample |p|^2
//    deferred to red_k; argmin is invariant to it). Mark batches that
//    contain at least one invisible vertex.
__global__ void pack_k(const float* __restrict__ verts,
                       const float* __restrict__ visible,
                       float4* __restrict__ packed,
                       int* __restrict__ flags) {
    int i = blockIdx.x * blockDim.x + threadIdx.x;
    if (i >= NVG) return;
    float x = verts[3 * i + 0];
    float y = verts[3 * i + 1];
    float z = verts[3 * i + 2];
    float w;
    if (visible[i] > 0.0f) {
        w = x * x + y * y + z * z;
    } else {
        w = 1e30f;                 // never wins the min (|2<p,v>| << 1e30)
        flags[i / NV] = 1;         // racy idempotent store
    }
    packed[i] = make_float4(-2.0f * x, -2.0f * y, -2.0f * z, w);
}

// 4) main: each thread owns P=8 samples; block loops over a vertex chunk in
//    LDS tiles. Per vertex: 1 broadcast LDS read feeds 8 independent
//    3-fma + fmin chains (ILP hides LDS + fmin latency at 1 wave/SIMD).
__global__ __launch_bounds__(256) void
main_k(const float4* __restrict__ bds,
       const float4* __restrict__ packed,
       unsigned int* __restrict__ minKeys) {
    __shared__ float4 sh[256];
    const int b  = blockIdx.z;
    const int v0 = blockIdx.x * CHUNK;
    const int v1 = min(v0 + CHUNK, NV);

    float px[P], py[P], pz[P], mn[P];
    #pragma unroll
    for (int u = 0; u < P; ++u) {
        float4 p = bds[b * SMP + u * 256 + threadIdx.x];
        px[u] = p.x; py[u] = p.y; pz[u] = p.z;
        mn[u] = 3.0e38f;
    }

    const float4* vp = packed + b * NV;
    for (int t = v0; t < v1; t += 256) {
        int idx = t + threadIdx.x;
        if (idx < v1) sh[threadIdx.x] = vp[idx];
        __syncthreads();
        int cnt = min(256, v1 - t);
        #pragma unroll 2
        for (int j = 0; j < cnt; ++j) {
            float4 v = sh[j];                       // broadcast read
            #pragma unroll
            for (int u = 0; u < P; ++u) {
                float q = fmaf(px[u], v.x,
                          fmaf(py[u], v.y,
                          fmaf(pz[u], v.z, v.w)));  // |v|^2 - 2<p,v>
                mn[u] = fminf(mn[u], q);
            }
        }
        __syncthreads();
    }
    #pragma unroll
    for (int u = 0; u < P; ++u)
        atomicMin(&minKeys[b * SMP + u * 256 + threadIdx.x], enc_f32(mn[u]));
}

// 5) final reduce: add back |p|^2, apply MASK_PENALTY clamp, masked sum / BT.
__global__ void red_k(const unsigned int* __restrict__ minKeys,
                      const float4* __restrict__ bds,
                      const int* __restrict__ flags,
                      float* __restrict__ out) {
    const int tid = threadIdx.x;                 // blockDim = 1024
    float sum = 0.0f;
    for (int i = tid; i < BT * SMP; i += 1024) {
        int b = i >> 11;                         // i / SMP
        float4 p = bds[i];
        float bs = p.x * p.x + p.y * p.y + p.z * p.z;
        float mn = dec_f32(minKeys[i]) + bs;     // true min d2
        if (flags[b]) mn = fminf(mn, 1000.0f);   // exact MASK_PENALTY path
        sum = fmaf(mn, p.w, sum);                // p.w = sample mask
    }
    #pragma unroll
    for (int o = 32; o > 0; o >>= 1) sum += __shfl_down(sum, o, 64);
    __shared__ float part[16];
    if ((tid & 63) == 0) part[tid >> 6] = sum;
    __syncthreads();
    if (tid == 0) {
        float t = 0.0f;
        #pragma unroll
        for (int i = 0; i < 16; ++i) t += part[i];
        out[0] = t / (float)BT;
    }
}

extern "C" void kernel_launch(void* const* d_in, const int* in_sizes, int n_in,
                              void* d_out, int out_size, void* d_ws, size_t ws_size,
                              hipStream_t stream) {
    const float* verts = (const float*)d_in[0];   // (4,20000,3) f32
    const float* bds   = (const float*)d_in[1];   // (4,2048,4)  f32
    const int*   faces = (const int*)d_in[2];     // (4,40000,3) int
    const int*   p2f   = (const int*)d_in[3];     // (4,256,256,1) int
    float*       out   = (float*)d_out;

    // workspace layout
    char* ws = (char*)d_ws;
    unsigned int* minKeys = (unsigned int*)ws;                    // 32768 B
    int*    flags   = (int*)(ws + 32768);                         // 16 B
    float4* packed  = (float4*)(ws + 32800);                      // 1,280,000 B
    float*  visible = (float*)(ws + 32800 + 1280000);             // 320,000 B

    init_k<<<(NVG + 255) / 256, 256, 0, stream>>>(minKeys, flags, visible);
    vis_k<<<(NPIX + 255) / 256, 256, 0, stream>>>(p2f, faces, visible);
    pack_k<<<(NVG + 255) / 256, 256, 0, stream>>>(verts, visible, packed, flags);
    main_k<<<dim3(NCH, 1, BT), 256, 0, stream>>>(
        (const float4*)bds, packed, minKeys);
    red_k<<<1, 1024, 0, stream>>>(minKeys, (const float4*)bds, flags, out);
}